// Round 14
// baseline (314.864 us; speedup 1.0000x reference)
//
#include <hip/hip_runtime.h>

#define N_NODES_C 50000
#define N_EDGES_C 800000
#define N_EDGES2_C (2 * N_EDGES_C)
#define D 128
#define NSHARD 8
#define OFCAP 4096 // overflow list capacity (expected use ~3 edges)

// Bucketed append: BROWS rows per bucket, per-XCD sub-buckets.
#define BROWS 4
#define NBKT (N_NODES_C / BROWS)   // 12500 (exact)
#define NSB (NSHARD * NBKT)        // 100000 sub-buckets
#define BCAP 32                    // entries per sub-bucket (mean 16, +4 sigma)

#define GNODES 64
#define LDP 132                                            // pad: multiple of 4 floats
#define GGRID ((N_NODES_C + GNODES - 1) / GNODES)          // 782 gemm blocks
#define FGRID 2048                                         // fill blocks
#define FEPB ((N_EDGES2_C + FGRID - 1) / FGRID)            // 782 edges/block
#define TOTG (GGRID + FGRID)                               // 2830

static __device__ __forceinline__ unsigned short f2bf(float f) {
  unsigned u = __float_as_uint(f);
  u += 0x7fff + ((u >> 16) & 1);  // round-to-nearest-even
  return (unsigned short)(u >> 16);
}
static __device__ __forceinline__ float bf_lo(unsigned u) {
  return __uint_as_float(u << 16);
}
static __device__ __forceinline__ float bf_hi(unsigned u) {
  return __uint_as_float(u & 0xffff0000u);
}

// Physical XCD id (0..7), wave-uniform; steers L2 locality of the shards.
static __device__ __forceinline__ int xcd_id() {
  int v;
  asm volatile("s_getreg_b32 %0, hwreg(HW_REG_XCC_ID, 0, 4)" : "=s"(v));
  return v & (NSHARD - 1);
}

// ---------------------------------------------------------------------------
// Kernel 1: alpha[i] = sigmoid(dot(x[i], alpha_w) + alpha_b), wave per node,
// PLUS zeroing of bcursor[NSB] and ofcnt (adjacent in ws). (R6/R9 verified.)
// ---------------------------------------------------------------------------
__global__ __launch_bounds__(256) void alpha_zero_kernel(
    const float* __restrict__ x,
    const float* __restrict__ aw,
    const float* __restrict__ ab,
    float* __restrict__ alpha_out,
    float* __restrict__ alpha_ws,
    int* __restrict__ bcursor,   // zeroes [0, NSB + 64) ints (incl ofcnt)
    int n) {
  int gtid = blockIdx.x * blockDim.x + threadIdx.x;
  if (gtid < NSB + 64) bcursor[gtid] = 0;

  int wave = gtid >> 6;
  int lane = threadIdx.x & 63;
  if (wave >= n) return;
  const float* xr = x + (size_t)wave * D;
  float s = xr[lane] * aw[lane] + xr[lane + 64] * aw[lane + 64];
  #pragma unroll
  for (int off = 32; off > 0; off >>= 1)
    s += __shfl_down(s, off);
  if (lane == 0) {
    float a = 1.0f / (1.0f + __expf(-(s + ab[0])));
    alpha_out[wave] = a;
    alpha_ws[wave] = a;
  }
}

// ---------------------------------------------------------------------------
// Kernel 2 (FUSED, block-specialized): GGRID gemm blocks + FGRID fill blocks,
// Bresenham-interleaved. (R6/R9 verified body.)
// Template YF32: y stored as f32 [N][128] (float4 store, no f2bf) when the
// workspace is big enough — halves gather's per-entry VALU (no bf16 unpack).
// ---------------------------------------------------------------------------
template <bool YF32>
__global__ __launch_bounds__(256) void gemm_fill_kernel(
    const float* __restrict__ x,
    const float* __restrict__ W,
    unsigned* __restrict__ y,        // [N][64] packed bf16 words (YF32=false)
    float* __restrict__ yf,          // [N][128] f32 (YF32=true)
    const int* __restrict__ lp_rows, const int* __restrict__ lp_cols,
    const float* __restrict__ lp_vals,
    const int* __restrict__ hp_rows, const int* __restrict__ hp_cols,
    const float* __restrict__ hp_vals,
    const float* __restrict__ alpha,
    int* __restrict__ bcursor,       // [NSB], zeroed
    uint2* __restrict__ bins,        // [NSB][BCAP]
    int* __restrict__ ofcnt,
    uint2* __restrict__ ofl,
    int n) {
  __shared__ float zs[GNODES][LDP];  // 33.8 KB
  __shared__ float wt[64][LDP];      // 33.8 KB (one j-half of W)

  int t = threadIdx.x;
  int bid = blockIdx.x;
  // Bresenham role split: exactly GGRID gemm blocks spread evenly.
  int g = (bid * GGRID) / TOTG;
  int gn = ((bid + 1) * GGRID) / TOTG;

  if (gn > g) {
    // ---------------- gemm block: nodes [g*64, g*64+64) ----------------
    int node0 = g * GNODES;
    int tn = t & 15;
    int tjg = t >> 4;   // 0..15
    int jb = tjg * 4;   // local j base within this half

    #pragma unroll
    for (int it = 0; it < 8; ++it) {
      int f = t + it * 256;
      int r = f >> 5;
      int c4 = f & 31;
      int node = node0 + r;
      float4 v = make_float4(0.f, 0.f, 0.f, 0.f);
      if (node < n) v = ((const float4*)(x + (size_t)node * D))[c4];
      *(float4*)&zs[r][c4 * 4] = v;
    }

    for (int jh = 0; jh < 2; ++jh) {
      if (jh) __syncthreads();  // half 0's wt readers done before overwrite
      #pragma unroll
      for (int it = 0; it < 8; ++it) {
        int f = t + it * 256;
        int j = f >> 5;
        int k4 = f & 31;
        *(float4*)&wt[j][k4 * 4] =
            ((const float4*)W)[(size_t)(jh * 64 + j) * 32 + k4];
      }
      __syncthreads();

      float acc[4][4] = {};
      #pragma unroll 2
      for (int k = 0; k < D; k += 4) {
        float4 w0 = *(const float4*)&wt[jb + 0][k];
        float4 w1 = *(const float4*)&wt[jb + 1][k];
        float4 w2 = *(const float4*)&wt[jb + 2][k];
        float4 w3 = *(const float4*)&wt[jb + 3][k];
        float4 z0 = *(const float4*)&zs[tn][k];
        float4 z1 = *(const float4*)&zs[tn + 16][k];
        float4 z2 = *(const float4*)&zs[tn + 32][k];
        float4 z3 = *(const float4*)&zs[tn + 48][k];
        acc[0][0] += z0.x*w0.x + z0.y*w0.y + z0.z*w0.z + z0.w*w0.w;
        acc[0][1] += z0.x*w1.x + z0.y*w1.y + z0.z*w1.z + z0.w*w1.w;
        acc[0][2] += z0.x*w2.x + z0.y*w2.y + z0.z*w2.z + z0.w*w2.w;
        acc[0][3] += z0.x*w3.x + z0.y*w3.y + z0.z*w3.z + z0.w*w3.w;
        acc[1][0] += z1.x*w0.x + z1.y*w0.y + z1.z*w0.z + z1.w*w0.w;
        acc[1][1] += z1.x*w1.x + z1.y*w1.y + z1.z*w1.z + z1.w*w1.w;
        acc[1][2] += z1.x*w2.x + z1.y*w2.y + z1.z*w2.z + z1.w*w2.w;
        acc[1][3] += z1.x*w3.x + z1.y*w3.y + z1.z*w3.z + z1.w*w3.w;
        acc[2][0] += z2.x*w0.x + z2.y*w0.y + z2.z*w0.z + z2.w*w0.w;
        acc[2][1] += z2.x*w1.x + z2.y*w1.y + z2.z*w1.z + z2.w*w1.w;
        acc[2][2] += z2.x*w2.x + z2.y*w2.y + z2.z*w2.z + z2.w*w2.w;
        acc[2][3] += z2.x*w3.x + z2.y*w3.y + z2.z*w3.z + z2.w*w3.w;
        acc[3][0] += z3.x*w0.x + z3.y*w0.y + z3.z*w0.z + z3.w*w0.w;
        acc[3][1] += z3.x*w1.x + z3.y*w1.y + z3.z*w1.z + z3.w*w1.w;
        acc[3][2] += z3.x*w2.x + z3.y*w2.y + z3.z*w2.z + z3.w*w2.w;
        acc[3][3] += z3.x*w3.x + z3.y*w3.y + z3.z*w3.z + z3.w*w3.w;
      }

      #pragma unroll
      for (int ii = 0; ii < 4; ++ii) {
        int node = node0 + ii * 16 + tn;
        if (node < n) {
          if constexpr (YF32) {
            // dims jh*64 + tjg*4 .. +3, 16B-aligned float4
            *(float4*)&yf[(size_t)node * D + jh * 64 + tjg * 4] =
                make_float4(acc[ii][0], acc[ii][1], acc[ii][2], acc[ii][3]);
          } else {
            uint2 o;
            o.x = (unsigned)f2bf(acc[ii][0]) | ((unsigned)f2bf(acc[ii][1]) << 16);
            o.y = (unsigned)f2bf(acc[ii][2]) | ((unsigned)f2bf(acc[ii][3]) << 16);
            *(uint2*)&y[(size_t)node * 64 + jh * 32 + tjg * 2] = o;
          }
        }
      }
    }
  } else {
    // ---------------- fill block: edges [fb*FEPB, fb*FEPB+FEPB) --------
    int fb = bid - g;
    int xcc = xcd_id();
    int e0 = fb * FEPB;
    int e1 = e0 + FEPB;
    if (e1 > N_EDGES2_C) e1 = N_EDGES2_C;
    for (int e = e0 + t; e < e1; e += 256) {
      int r, c;
      float v;
      if (e < N_EDGES_C) {
        r = __builtin_nontemporal_load(lp_rows + e);
        c = __builtin_nontemporal_load(lp_cols + e);
        v = __builtin_nontemporal_load(lp_vals + e) * alpha[r];
      } else {
        int i = e - N_EDGES_C;
        r = __builtin_nontemporal_load(hp_rows + i);
        c = __builtin_nontemporal_load(hp_cols + i);
        v = __builtin_nontemporal_load(hp_vals + i) * (1.0f - alpha[r]);
      }
      int sb = xcc * NBKT + (r >> 2);
      int p = atomicAdd(&bcursor[sb], 1);
      if (p < BCAP) {
        bins[(size_t)sb * BCAP + p] =
            make_uint2(((unsigned)r << 16) | (unsigned)c, __float_as_uint(v));
      } else {
        int q = atomicAdd(ofcnt, 1);
        if (q < OFCAP)
          ofl[q] = make_uint2(((unsigned)r << 16) | (unsigned)c,
                              (unsigned)__float_as_int(v));
      }
    }
  }
}

// ---------------------------------------------------------------------------
// Kernel 3: gather — ONE WAVE PER BUCKET (4 rows), register accumulation,
// readlane decode at compile-time slot indices (R12-verified, −6 us).
// Template YF32: y is f32 [N][128] -> lane loads its dim pair with ONE
// global_load_dwordx2 and feeds 2 v_fmac directly — NO bf16 unpack. R11/R12
// established gather is per-entry-VALU bound; this halves per-entry VALU.
// NO atomics, NO LDS, NO barriers.
// ---------------------------------------------------------------------------
template <bool YF32>
__global__ __launch_bounds__(256) void gather_kernel(
    const int* __restrict__ bcursor,     // [NSHARD][NBKT]
    const uint2* __restrict__ bins,      // [NSB][BCAP]
    const unsigned* __restrict__ y,      // [N][64] bf16 words (YF32=false)
    const float* __restrict__ yf,        // [N][128] f32 (YF32=true)
    const float* __restrict__ bias,
    const int* __restrict__ ofcnt,
    const uint2* __restrict__ ofl,
    float* __restrict__ out) {
  int t = threadIdx.x;
  int w = t >> 6;
  int lane = t & 63;
  int bkt = blockIdx.x * 4 + w;   // 0..12499 (exact: 3125 blocks x 4 waves)

  float a0L = 0.f, a0H = 0.f, a1L = 0.f, a1H = 0.f;
  float a2L = 0.f, a2H = 0.f, a3L = 0.f, a3H = 0.f;

  #define ACC2(RR, VV, UL, UH)                                   \
    do {                                                         \
      switch (RR) {                                              \
        case 0: a0L += (VV) * (UL); a0H += (VV) * (UH); break;   \
        case 1: a1L += (VV) * (UL); a1H += (VV) * (UH); break;   \
        case 2: a2L += (VV) * (UL); a2H += (VV) * (UH); break;   \
        default: a3L += (VV) * (UL); a3H += (VV) * (UH); break;  \
      }                                                          \
    } while (0)

  int cnts[8];
  uint2 wvs[8];
  #pragma unroll
  for (int s = 0; s < 8; ++s) {
    int c = bcursor[s * NBKT + bkt];
    cnts[s] = c > BCAP ? BCAP : c;
  }
  #pragma unroll
  for (int s = 0; s < 8; ++s) {
    wvs[s] = make_uint2(0u, 0u);   // zero-pad: spurious slots add 0.0
    if (lane < cnts[s])
      wvs[s] = bins[(size_t)(s * NBKT + bkt) * BCAP + lane];
  }

  #pragma unroll
  for (int s = 0; s < 8; ++s) {
    int cnt = cnts[s];
    uint2 wv = wvs[s];
    #pragma unroll
    for (int b = 0; b < BCAP; b += 4) {
      if (cnt <= b) break;  // wave-uniform early-out per 4-entry batch
      unsigned xk0 = __builtin_amdgcn_readlane(wv.x, b + 0);
      unsigned xk1 = __builtin_amdgcn_readlane(wv.x, b + 1);
      unsigned xk2 = __builtin_amdgcn_readlane(wv.x, b + 2);
      unsigned xk3 = __builtin_amdgcn_readlane(wv.x, b + 3);
      unsigned vb0 = __builtin_amdgcn_readlane(wv.y, b + 0);
      unsigned vb1 = __builtin_amdgcn_readlane(wv.y, b + 1);
      unsigned vb2 = __builtin_amdgcn_readlane(wv.y, b + 2);
      unsigned vb3 = __builtin_amdgcn_readlane(wv.y, b + 3);
      if constexpr (YF32) {
        float2 u0 = *(const float2*)(yf + (size_t)(xk0 & 0xffffu) * D + lane * 2);
        float2 u1 = *(const float2*)(yf + (size_t)(xk1 & 0xffffu) * D + lane * 2);
        float2 u2 = *(const float2*)(yf + (size_t)(xk2 & 0xffffu) * D + lane * 2);
        float2 u3 = *(const float2*)(yf + (size_t)(xk3 & 0xffffu) * D + lane * 2);
        ACC2((int)((xk0 >> 16) & 3), __uint_as_float(vb0), u0.x, u0.y);
        ACC2((int)((xk1 >> 16) & 3), __uint_as_float(vb1), u1.x, u1.y);
        ACC2((int)((xk2 >> 16) & 3), __uint_as_float(vb2), u2.x, u2.y);
        ACC2((int)((xk3 >> 16) & 3), __uint_as_float(vb3), u3.x, u3.y);
      } else {
        unsigned u0 = y[(size_t)(xk0 & 0xffffu) * 64 + lane];
        unsigned u1 = y[(size_t)(xk1 & 0xffffu) * 64 + lane];
        unsigned u2 = y[(size_t)(xk2 & 0xffffu) * 64 + lane];
        unsigned u3 = y[(size_t)(xk3 & 0xffffu) * 64 + lane];
        ACC2((int)((xk0 >> 16) & 3), __uint_as_float(vb0), bf_lo(u0), bf_hi(u0));
        ACC2((int)((xk1 >> 16) & 3), __uint_as_float(vb1), bf_lo(u1), bf_hi(u1));
        ACC2((int)((xk2 >> 16) & 3), __uint_as_float(vb2), bf_lo(u2), bf_hi(u2));
        ACC2((int)((xk3 >> 16) & 3), __uint_as_float(vb3), bf_lo(u3), bf_hi(u3));
      }
    }
  }

  // overflow entries (expected ~0-10 total): every wave scans, matches own bucket
  int nof = *ofcnt;
  if (nof > OFCAP) nof = OFCAP;
  for (int i = 0; i < nof; ++i) {
    uint2 o = ofl[i];
    unsigned r = o.x >> 16;
    if ((int)(r >> 2) == bkt) {
      float v = __uint_as_float(o.y);
      if constexpr (YF32) {
        float2 u = *(const float2*)(yf + (size_t)(o.x & 0xffffu) * D + lane * 2);
        ACC2((int)(r & 3), v, u.x, u.y);
      } else {
        unsigned u = y[(size_t)(o.x & 0xffffu) * 64 + lane];
        ACC2((int)(r & 3), v, bf_lo(u), bf_hi(u));
      }
    }
  }
  #undef ACC2

  float2 bv = *(const float2*)&bias[lane * 2];
  size_t ro = (size_t)bkt * 4 * D + lane * 2;
  float2 o0, o1, o2, o3;
  o0.x = fmaxf(a0L + bv.x, 0.0f); o0.y = fmaxf(a0H + bv.y, 0.0f);
  o1.x = fmaxf(a1L + bv.x, 0.0f); o1.y = fmaxf(a1H + bv.y, 0.0f);
  o2.x = fmaxf(a2L + bv.x, 0.0f); o2.y = fmaxf(a2H + bv.y, 0.0f);
  o3.x = fmaxf(a3L + bv.x, 0.0f); o3.y = fmaxf(a3H + bv.y, 0.0f);
  *(float2*)&out[ro + 0 * D] = o0;
  *(float2*)&out[ro + 1 * D] = o1;
  *(float2*)&out[ro + 2 * D] = o2;
  *(float2*)&out[ro + 3 * D] = o3;
}

extern "C" void kernel_launch(void* const* d_in, const int* in_sizes, int n_in,
                              void* d_out, int out_size, void* d_ws, size_t ws_size,
                              hipStream_t stream) {
  const float* x = (const float*)d_in[0];
  const int* lp_rows = (const int*)d_in[1];
  const int* lp_cols = (const int*)d_in[2];
  const float* lp_vals = (const float*)d_in[3];
  const int* hp_rows = (const int*)d_in[4];
  const int* hp_cols = (const int*)d_in[5];
  const float* hp_vals = (const float*)d_in[6];
  const float* alpha_w = (const float*)d_in[7];
  const float* alpha_b = (const float*)d_in[8];
  const float* W = (const float*)d_in[9];
  const float* bias = (const float*)d_in[10];

  float* out = (float*)d_out;                      // [N, 128]
  float* alpha_out = out + (size_t)N_NODES_C * D;  // [N, 1] output tail

  // Layout A (f32 y): 25.6M + 200K + 400K + 256 + 32K + 25.6M ~= 51.9 MB.
  // Layout B (bf16 y, R12-identical): ~40.2 MB (proven safe).
  const size_t szY_f32 = (size_t)N_NODES_C * D * 4;
  const size_t szY_bf16 = (size_t)N_NODES_C * 64 * 4;
  const size_t szTail = 200192 + (size_t)NSB * 4 + 256 + (size_t)OFCAP * 8 +
                        (size_t)NSB * BCAP * 8;
  bool f32path = ws_size >= szY_f32 + szTail + 65536;

  char* ws = (char*)d_ws;
  float* yf = (float*)ws;
  unsigned* yb = (unsigned*)ws;
  ws += f32path ? szY_f32 : szY_bf16;
  float* alpha_ws = (float*)ws;  ws += 200192;
  int* bcursor = (int*)ws;       ws += (size_t)NSB * 4;
  int* ofcnt = (int*)ws;         ws += 256;        // adjacent to bcursor
  uint2* ofl = (uint2*)ws;       ws += (size_t)OFCAP * 8;
  uint2* bins = (uint2*)ws;      ws += (size_t)NSB * BCAP * 8;

  // Dispatch 1: alpha + cursor/ofcnt zeroing
  alpha_zero_kernel<<<(N_NODES_C + 3) / 4, 256, 0, stream>>>(
      x, alpha_w, alpha_b, alpha_out, alpha_ws, bcursor, N_NODES_C);

  if (f32path) {
    gemm_fill_kernel<true><<<TOTG, 256, 0, stream>>>(
        x, W, nullptr, yf,
        lp_rows, lp_cols, lp_vals, hp_rows, hp_cols, hp_vals,
        alpha_ws, bcursor, bins, ofcnt, ofl, N_NODES_C);
    gather_kernel<true><<<NBKT / 4, 256, 0, stream>>>(
        bcursor, bins, nullptr, yf, bias, ofcnt, ofl, out);
  } else {
    gemm_fill_kernel<false><<<TOTG, 256, 0, stream>>>(
        x, W, yb, nullptr,
        lp_rows, lp_cols, lp_vals, hp_rows, hp_cols, hp_vals,
        alpha_ws, bcursor, bins, ofcnt, ofl, N_NODES_C);
    gather_kernel<false><<<NBKT / 4, 256, 0, stream>>>(
        bcursor, bins, yb, nullptr, bias, ofcnt, ofl, out);
  }
}